// Round 9
// baseline (157.664 us; speedup 1.0000x reference)
//
#include <hip/hip_runtime.h>

typedef short bf16x8 __attribute__((ext_vector_type(8)));
typedef float f32x4  __attribute__((ext_vector_type(4)));

#define NSTEP 25
#define SROW  264               // padded LDS row stride in shorts
#define LDSB  (16 * SROW)       // shorts per buffer (16 rows)

__device__ __forceinline__ unsigned short f2bf(float x) {
    union { float f; unsigned int u; } v; v.f = x;
    unsigned int r = v.u + 0x7FFFu + ((v.u >> 16) & 1u);   // RNE
    return (unsigned short)(r >> 16);
}

#if __has_builtin(__builtin_amdgcn_cvt_pk_bf16_f32)
typedef __bf16 bfv2 __attribute__((ext_vector_type(2)));
__device__ __forceinline__ unsigned short f2bf1(float a) {
    union { bfv2 v; unsigned int u; } c;
    c.v = __builtin_amdgcn_cvt_pk_bf16_f32(a, a);   // lo=a (RNE), 1 instr
    return (unsigned short)c.u;
}
#else
__device__ __forceinline__ unsigned short f2bf1(float a) { return f2bf(a); }
#endif

#if __has_builtin(__builtin_amdgcn_exp2f)
#define EXP2F __builtin_amdgcn_exp2f
#else
#define EXP2F exp2f
#endif

#define C2LOG2E 2.8853900817779268f   // 2*log2(e)

// tanh(y + bt) with pre-scaled bias btc = bt * 2*log2(e):
//   tanh(x) = 1 - 2/(exp2(x * 2log2e) + 1)
__device__ __forceinline__ float tanh_pre(float y, float btc) {
    float e = EXP2F(fmaf(y, C2LOG2E, btc));
    return 1.0f - 2.0f * __builtin_amdgcn_rcpf(e + 1.0f);
}

// One prep dispatch (769 blocks x 256 threads):
//  b in [0,257):   b<256: W21' = dt*(W2@W1) row b -> frag layout; b==256: c1 = b2@W1.
//                  K-loop batched 16-wide with 4 independent accumulators.
//  b in [257,769): sigma-permuted fragment-ordered bf16 W1r/W2r
// Layout (verified): Wr[kc*8192 + n*32 + q*8 + j] = W[sigma_inv(kc*32+q*8+j)][n]
// sigma(k) = (k & ~31) | ((k&15)<<1) | ((k>>4)&1)
__global__ void prep_all(const float* __restrict__ W1,
                         const float* __restrict__ W2,
                         const float* __restrict__ b2,
                         const float* __restrict__ t_range,
                         unsigned short* __restrict__ Wr,
                         unsigned short* __restrict__ W21r,
                         float* __restrict__ c1)
{
    __shared__ float row[256];
    int b = blockIdx.x;
    if (b < 257) {
        int i = b, j = threadIdx.x;
        row[j] = (i < 256) ? W2[i * 256 + j] : b2[j];
        __syncthreads();
        float a0 = 0.f, a1 = 0.f, a2 = 0.f, a3 = 0.f;
#pragma unroll
        for (int d = 0; d < 256; d += 16) {
            float w[16];
#pragma unroll
            for (int u = 0; u < 16; ++u) w[u] = W1[(d + u) * 256 + j];
#pragma unroll
            for (int u = 0; u < 16; u += 4) {
                a0 = fmaf(row[d + u + 0], w[u + 0], a0);
                a1 = fmaf(row[d + u + 1], w[u + 1], a1);
                a2 = fmaf(row[d + u + 2], w[u + 2], a2);
                a3 = fmaf(row[d + u + 3], w[u + 3], a3);
            }
        }
        float acc = (a0 + a1) + (a2 + a3);
        if (i < 256) {
            float dt = t_range[1] - t_range[0];
            int p  = (i & ~31) | ((i & 15) << 1) | ((i >> 4) & 1);
            int kc = p >> 5, q = (p >> 3) & 3, jj = p & 7;
            W21r[kc * 8192 + j * 32 + q * 8 + jj] = f2bf(dt * acc);
        } else {
            c1[j] = acc;
        }
    } else {
        int bb = b - 257;            // 0..511
        const float* src = (bb < 256) ? W1 : W2;
        unsigned short* dst = Wr + ((bb < 256) ? 0 : 65536);
        int k = bb & 255;
        int n = threadIdx.x;
        int p  = (k & ~31) | ((k & 15) << 1) | ((k >> 4) & 1);
        int kc = p >> 5, q = (p >> 3) & 3, jj = p & 7;
        dst[kc * 8192 + n * 32 + q * 8 + jj] = f2bf(src[k * 256 + n]);
    }
}

// R9 occupancy doubling: 1024 blocks x 16 rows, 1024 threads = 16 waves.
// Wave w owns cols [16w, 16w+16) of the block's 16 rows:
//   w21f = 8 frags = 32 VGPRs (was 64), y/S = one f32x4 each.
// Total ~60 regs -> __launch_bounds__(1024, 8) caps at 64 -> 32 waves/CU
// (2 blocks x 16 waves = 2048 threads = CU max), double R1's 16 waves/CU.
// Per-CU LDS/VALU/MFMA totals conserved vs R1; only wave-parallelism changes.
// sigma-interleaved LDS position of natural col c within its 32-group:
//   pos(c) = (c & ~31) | ((c & 15) << 1) | ((c >> 4) & 1)
// -> wave w (group g=w>>1, half=w&1), lane l15: pos = g*32 + 2*l15 + half.
__global__ __launch_bounds__(1024, 8) void ode_main(
    const float* __restrict__ z0,
    const float* __restrict__ t_range,
    const float* __restrict__ b1,
    const float* __restrict__ wt,
    const float* __restrict__ b2,
    const unsigned short* __restrict__ W1r,
    const unsigned short* __restrict__ W2r,
    const unsigned short* __restrict__ W21r,
    const float* __restrict__ c1,
    float* __restrict__ out)
{
    __shared__ __align__(16) unsigned short As[2 * LDSB];   // 16.5 KiB double-buffered

    const int tid  = threadIdx.x;
    const int wave = tid >> 6;        // 0..15
    const int lane = tid & 63;
    const int q    = lane >> 4;
    const int l15  = lane & 15;
    const int row0 = blockIdx.x * 16;
    const int n0   = wave * 16;       // natural col base
    const int g    = wave >> 1, half = wave & 1;

    // hot-loop LDS bases (all accesses = base + [buf/r/kc] offsets)
    unsigned short* const       hw = &As[(q * 4) * SROW + g * 32 + 2 * l15 + half];
    const unsigned short* const ar = &As[l15 * SROW + q * 8];

    const float dt = t_range[1] - t_range[0];

    // pre-scaled bias recurrence for this thread's single col n:
    // btc_s = (b1 + s*dt*(wt + c1)) * 2log2e
    const int n = n0 + l15;
    float btc  = b1[n] * C2LOG2E;
    float dbtc = dt * (wt[n] + c1[n]) * C2LOG2E;

    // ---- stage bf16(z0) into buf0: 4 rows x 1 col per thread ----
#pragma unroll
    for (int r = 0; r < 4; ++r)
        hw[r * SROW] = f2bf1(z0[(row0 + q * 4 + r) * 256 + n]);
    __syncthreads();

    // ---- y0 = z0 @ W1 (B-frags streamed from global, used once) ----
    f32x4 y = f32x4{0.f, 0.f, 0.f, 0.f};
#pragma unroll
    for (int kc = 0; kc < 8; ++kc) {
        bf16x8 a  = *(const bf16x8*)&ar[kc * 32];
        bf16x8 bb = *(const bf16x8*)&W1r[kc * 8192 + n * 32 + q * 8];
        y = __builtin_amdgcn_mfma_f32_16x16x32_bf16(a, bb, y, 0, 0, 0);
    }

    // ---- preload W21' fragments (32 VGPRs), resident for the whole loop ----
    bf16x8 w21f[8];
#pragma unroll
    for (int kc = 0; kc < 8; ++kc)
        w21f[kc] = *(const bf16x8*)&W21r[kc * 8192 + n * 32 + q * 8];

    f32x4 S = f32x4{0.f, 0.f, 0.f, 0.f};

    // ---- 24 full steps: tanh+stage -> barrier -> y += H @ W21' ----
    // step s stages/reads buf ((s+1)&1); single barrier/step (WAR on the
    // other buffer is covered by the previous step's barrier, as in R1).
    for (int s = 0; s < NSTEP - 1; ++s) {
        const int buf = ((s + 1) & 1) * LDSB;
#pragma unroll
        for (int r = 0; r < 4; ++r) {
            float h = tanh_pre(y[r], btc);
            S[r] += h;
            hw[buf + r * SROW] = f2bf1(h);
        }
        btc += dbtc;
        __syncthreads();

#pragma unroll
        for (int kc = 0; kc < 8; ++kc) {
            bf16x8 a = *(const bf16x8*)&ar[buf + kc * 32];
            y = __builtin_amdgcn_mfma_f32_16x16x32_bf16(a, w21f[kc], y, 0, 0, 0);
        }
    }

    // ---- last step: H_24 only feeds S ----
#pragma unroll
    for (int r = 0; r < 4; ++r)
        S[r] += tanh_pre(y[r], btc);

    // ---- epilogue: z_T = z0 + dt*(S @ W2) + NSTEP*dt*b2 ----
    {
        const int buf = LDSB;   // buf1 (last GEMM at s=23 read buf0)
#pragma unroll
        for (int r = 0; r < 4; ++r)
            hw[buf + r * SROW] = f2bf1(S[r]);
        __syncthreads();

        f32x4 acc = f32x4{0.f, 0.f, 0.f, 0.f};
#pragma unroll
        for (int kc = 0; kc < 8; ++kc) {
            bf16x8 a  = *(const bf16x8*)&ar[buf + kc * 32];
            bf16x8 bb = *(const bf16x8*)&W2r[kc * 8192 + n * 32 + q * 8];
            acc = __builtin_amdgcn_mfma_f32_16x16x32_bf16(a, bb, acc, 0, 0, 0);
        }

        const float cb2 = (float)NSTEP * dt;
        const float b2v = b2[n];
#pragma unroll
        for (int r = 0; r < 4; ++r) {
            int idx = (row0 + q * 4 + r) * 256 + n;
            out[idx] = z0[idx] + dt * acc[r] + cb2 * b2v;
        }
    }
}

extern "C" void kernel_launch(void* const* d_in, const int* in_sizes, int n_in,
                              void* d_out, int out_size, void* d_ws, size_t ws_size,
                              hipStream_t stream) {
    const float* z0      = (const float*)d_in[0];
    const float* t_range = (const float*)d_in[1];
    const float* W1      = (const float*)d_in[2];
    const float* b1      = (const float*)d_in[3];
    const float* wt      = (const float*)d_in[4];
    const float* W2      = (const float*)d_in[5];
    const float* b2      = (const float*)d_in[6];

    unsigned short* Wr = (unsigned short*)d_ws;
    // shorts: W1r [0,65536)  W2r [65536,131072)  W21r [131072,196608); then c1 (256 floats)
    unsigned short* W1r  = Wr;
    unsigned short* W2r  = Wr + 65536;
    unsigned short* W21r = Wr + 131072;
    float*          c1   = (float*)(Wr + 196608);

    prep_all<<<769, 256, 0, stream>>>(W1, W2, b2, t_range, Wr, W21r, c1);
    ode_main<<<1024, 1024, 0, stream>>>(z0, t_range, b1, wt, b2,
                                        W1r, W2r, W21r, c1, (float*)d_out);
}

// Round 10
// 145.394 us; speedup vs baseline: 1.0844x; 1.0844x over previous
//
#include <hip/hip_runtime.h>

typedef short bf16x8 __attribute__((ext_vector_type(8)));
typedef float f32x4  __attribute__((ext_vector_type(4)));

#define NSTEP 25
#define SROW  264               // padded LDS row stride in shorts
#define LDSB  (32 * SROW)       // shorts per buffer (32 rows)

__device__ __forceinline__ unsigned short f2bf(float x) {
    union { float f; unsigned int u; } v; v.f = x;
    unsigned int r = v.u + 0x7FFFu + ((v.u >> 16) & 1u);   // RNE
    return (unsigned short)(r >> 16);
}

#if __has_builtin(__builtin_amdgcn_cvt_pk_bf16_f32)
typedef __bf16 bfv2 __attribute__((ext_vector_type(2)));
__device__ __forceinline__ unsigned int pk2bf(float a, float b) {
    union { bfv2 v; unsigned int u; } c;
    c.v = __builtin_amdgcn_cvt_pk_bf16_f32(a, b);   // lo=a, hi=b, RNE
    return c.u;
}
#else
__device__ __forceinline__ unsigned int pk2bf(float a, float b) {
    return (unsigned int)f2bf(a) | ((unsigned int)f2bf(b) << 16);
}
#endif

#if __has_builtin(__builtin_amdgcn_exp2f)
#define EXP2F __builtin_amdgcn_exp2f
#else
#define EXP2F exp2f
#endif

#define C2LOG2E 2.8853900817779268f   // 2*log2(e)

// tanh(y + bt) with pre-scaled bias btc = bt * 2*log2(e):
//   tanh(x) = 1 - 2/(exp2(x * 2log2e) + 1)
// 1 fma + 1 v_exp + 1 add + 1 rcp + 1 fma
__device__ __forceinline__ float tanh_pre(float y, float btc) {
    float e = EXP2F(fmaf(y, C2LOG2E, btc));
    return 1.0f - 2.0f * __builtin_amdgcn_rcpf(e + 1.0f);
}

// One prep dispatch (769 blocks x 256 threads):
//  b in [0,257):   b<256: W21' = dt*(W2@W1) row b -> frag layout; b==256: c1 = b2@W1.
//                  K-loop batched 16-wide with 4 independent accumulators
//                  (longest pole launched first).
//  b in [257,769): sigma-permuted fragment-ordered bf16 W1r/W2r
// Layout (verified): Wr[kc*8192 + n*32 + q*8 + j] = W[sigma_inv(kc*32+q*8+j)][n]
// sigma(k) = (k & ~31) | ((k&15)<<1) | ((k>>4)&1)
__global__ void prep_all(const float* __restrict__ W1,
                         const float* __restrict__ W2,
                         const float* __restrict__ b2,
                         const float* __restrict__ t_range,
                         unsigned short* __restrict__ Wr,
                         unsigned short* __restrict__ W21r,
                         float* __restrict__ c1)
{
    __shared__ float row[256];
    int b = blockIdx.x;
    if (b < 257) {
        int i = b, j = threadIdx.x;
        row[j] = (i < 256) ? W2[i * 256 + j] : b2[j];
        __syncthreads();
        float a0 = 0.f, a1 = 0.f, a2 = 0.f, a3 = 0.f;
#pragma unroll
        for (int d = 0; d < 256; d += 16) {
            float w[16];
#pragma unroll
            for (int u = 0; u < 16; ++u) w[u] = W1[(d + u) * 256 + j];
#pragma unroll
            for (int u = 0; u < 16; u += 4) {
                a0 = fmaf(row[d + u + 0], w[u + 0], a0);
                a1 = fmaf(row[d + u + 1], w[u + 1], a1);
                a2 = fmaf(row[d + u + 2], w[u + 2], a2);
                a3 = fmaf(row[d + u + 3], w[u + 3], a3);
            }
        }
        float acc = (a0 + a1) + (a2 + a3);
        if (i < 256) {
            float dt = t_range[1] - t_range[0];
            int p  = (i & ~31) | ((i & 15) << 1) | ((i >> 4) & 1);
            int kc = p >> 5, q = (p >> 3) & 3, jj = p & 7;
            W21r[kc * 8192 + j * 32 + q * 8 + jj] = f2bf(dt * acc);
        } else {
            c1[j] = acc;
        }
    } else {
        int bb = b - 257;            // 0..511
        const float* src = (bb < 256) ? W1 : W2;
        unsigned short* dst = Wr + ((bb < 256) ? 0 : 65536);
        int k = bb & 255;
        int n = threadIdx.x;
        int p  = (k & ~31) | ((k & 15) << 1) | ((k >> 4) & 1);
        int kc = p >> 5, q = (p >> 3) & 3, jj = p & 7;
        dst[kc * 8192 + n * 32 + q * 8 + jj] = f2bf(src[k * 256 + n]);
    }
}

// 512 threads = 8 waves; wave w owns cols [32w, 32w+32) of the block's 32 rows.
// w21f = 64 VGPRs resident for the whole loop.
// State: y = z@W1 (c1 drift folded into bt), S = sum of H.
// Hot loop: tanh+stage bf16(H) -> 1 barrier -> y += H @ W21' (MFMA-accumulate).
// SESSION EVIDENCE (R1-R9): this shape is the measured optimum. Null/negative:
// phase stagger+setprio (R2), fat-wave LDS-halving (R3 — not LDS-BW-bound),
// band pipeline (R4), deferred-write pipeline (R5 — scratch), dual-tile
// antiphase (R6), paired-rcp VALU diet (R7), occupancy x2 via thin waves
// (R9 — 76% occ but SLOWER; not latency-hiding-bound). Plateau is the serial
// 25-step barrier chain, not any pipe roofline (all <50%).
__global__ __launch_bounds__(512, 4) void ode_main(
    const float* __restrict__ z0,
    const float* __restrict__ t_range,
    const float* __restrict__ b1,
    const float* __restrict__ wt,
    const float* __restrict__ b2,
    const unsigned short* __restrict__ W1r,
    const unsigned short* __restrict__ W2r,
    const unsigned short* __restrict__ W21r,
    const float* __restrict__ c1,
    float* __restrict__ out)
{
    __shared__ __align__(16) unsigned short As[2 * LDSB];   // 33 KiB double-buffered

    const int tid  = threadIdx.x;
    const int wave = tid >> 6;        // 0..7
    const int lane = tid & 63;
    const int q    = lane >> 4;
    const int l15  = lane & 15;
    const int row0 = blockIdx.x * 32;
    const int n0   = wave * 32;

    const float dt = t_range[1] - t_range[0];

    // pre-scaled bias recurrence: btc_s = (b1 + s*dt*(wt + c1)) * 2log2e
    float btc[2], dbtc[2];
#pragma unroll
    for (int tt = 0; tt < 2; ++tt) {
        int n = n0 + tt * 16 + l15;
        btc[tt]  = b1[n] * C2LOG2E;
        dbtc[tt] = dt * (wt[n] + c1[n]) * C2LOG2E;
    }

    // ---- stage bf16(z0) into buf0 ----
#pragma unroll
    for (int band = 0; band < 2; ++band)
#pragma unroll
        for (int r = 0; r < 4; ++r) {
            int m = band * 16 + q * 4 + r;
            const float* zr = &z0[(row0 + m) * 256 + n0];
            *(unsigned int*)&As[m * SROW + n0 + l15 * 2] =
                pk2bf(zr[l15], zr[16 + l15]);
        }
    __syncthreads();

    // ---- y0 = z0 @ W1 (B-frags streamed from global, used once) ----
    f32x4 y[2][2];
#pragma unroll
    for (int band = 0; band < 2; ++band)
#pragma unroll
        for (int tt = 0; tt < 2; ++tt) y[band][tt] = f32x4{0.f, 0.f, 0.f, 0.f};
#pragma unroll
    for (int kc = 0; kc < 8; ++kc) {
        bf16x8 a[2];
#pragma unroll
        for (int band = 0; band < 2; ++band)
            a[band] = *(const bf16x8*)&As[(band * 16 + l15) * SROW + kc * 32 + q * 8];
#pragma unroll
        for (int tt = 0; tt < 2; ++tt) {
            bf16x8 bb = *(const bf16x8*)&W1r[kc * 8192 + (n0 + tt * 16 + l15) * 32 + q * 8];
#pragma unroll
            for (int band = 0; band < 2; ++band)
                y[band][tt] = __builtin_amdgcn_mfma_f32_16x16x32_bf16(
                    a[band], bb, y[band][tt], 0, 0, 0);
        }
    }

    // ---- preload W21' fragments (64 VGPRs), resident for the whole loop ----
    bf16x8 w21f[8][2];
#pragma unroll
    for (int kc = 0; kc < 8; ++kc)
#pragma unroll
        for (int tt = 0; tt < 2; ++tt)
            w21f[kc][tt] = *(const bf16x8*)&W21r[kc * 8192 + (n0 + tt * 16 + l15) * 32 + q * 8];

    f32x4 S[2][2];
#pragma unroll
    for (int band = 0; band < 2; ++band)
#pragma unroll
        for (int tt = 0; tt < 2; ++tt) S[band][tt] = f32x4{0.f, 0.f, 0.f, 0.f};

    // ---- 24 full steps: H -> stage -> y += H @ W21' (MFMA-accumulate) ----
    for (int s = 0; s < NSTEP - 1; ++s) {
        const int buf = ((s + 1) & 1) * LDSB;
#pragma unroll
        for (int band = 0; band < 2; ++band)
#pragma unroll
            for (int r = 0; r < 4; ++r) {
                int m = band * 16 + q * 4 + r;
                float h0 = tanh_pre(y[band][0][r], btc[0]);
                float h1 = tanh_pre(y[band][1][r], btc[1]);
                S[band][0][r] += h0; S[band][1][r] += h1;
                *(unsigned int*)&As[buf + m * SROW + n0 + l15 * 2] = pk2bf(h0, h1);
            }
        __syncthreads();

#pragma unroll
        for (int kc = 0; kc < 8; ++kc) {
            bf16x8 a[2];
#pragma unroll
            for (int band = 0; band < 2; ++band)
                a[band] = *(const bf16x8*)&As[buf + (band * 16 + l15) * SROW + kc * 32 + q * 8];
#pragma unroll
            for (int band = 0; band < 2; ++band)
#pragma unroll
                for (int tt = 0; tt < 2; ++tt)
                    y[band][tt] = __builtin_amdgcn_mfma_f32_16x16x32_bf16(
                        a[band], w21f[kc][tt], y[band][tt], 0, 0, 0);
        }

#pragma unroll
        for (int tt = 0; tt < 2; ++tt) btc[tt] += dbtc[tt];
    }

    // ---- last step: H only feeds S ----
#pragma unroll
    for (int band = 0; band < 2; ++band)
#pragma unroll
        for (int r = 0; r < 4; ++r)
#pragma unroll
            for (int tt = 0; tt < 2; ++tt)
                S[band][tt][r] += tanh_pre(y[band][tt][r], btc[tt]);

    // ---- epilogue: z_T = z0 + dt*(S @ W2) + NSTEP*dt*b2 ----
    {
        const int buf = LDSB;   // buf1 (last GEMM at s=23 read buf0)
#pragma unroll
        for (int band = 0; band < 2; ++band)
#pragma unroll
            for (int r = 0; r < 4; ++r) {
                int m = band * 16 + q * 4 + r;
                *(unsigned int*)&As[buf + m * SROW + n0 + l15 * 2] =
                    pk2bf(S[band][0][r], S[band][1][r]);
            }
        __syncthreads();

        f32x4 acc[2][2];
#pragma unroll
        for (int band = 0; band < 2; ++band)
#pragma unroll
            for (int tt = 0; tt < 2; ++tt) acc[band][tt] = f32x4{0.f, 0.f, 0.f, 0.f};
#pragma unroll
        for (int kc = 0; kc < 8; ++kc) {
            bf16x8 a[2];
#pragma unroll
            for (int band = 0; band < 2; ++band)
                a[band] = *(const bf16x8*)&As[buf + (band * 16 + l15) * SROW + kc * 32 + q * 8];
#pragma unroll
            for (int tt = 0; tt < 2; ++tt) {
                bf16x8 bb = *(const bf16x8*)&W2r[kc * 8192 + (n0 + tt * 16 + l15) * 32 + q * 8];
#pragma unroll
                for (int band = 0; band < 2; ++band)
                    acc[band][tt] = __builtin_amdgcn_mfma_f32_16x16x32_bf16(
                        a[band], bb, acc[band][tt], 0, 0, 0);
            }
        }

        const float cb2 = (float)NSTEP * dt;
#pragma unroll
        for (int band = 0; band < 2; ++band)
#pragma unroll
            for (int tt = 0; tt < 2; ++tt) {
                float b2v = b2[n0 + tt * 16 + l15];
#pragma unroll
                for (int r = 0; r < 4; ++r) {
                    int idx = (row0 + band * 16 + q * 4 + r) * 256 + n0 + tt * 16 + l15;
                    out[idx] = z0[idx] + dt * acc[band][tt][r] + cb2 * b2v;
                }
            }
    }
}

extern "C" void kernel_launch(void* const* d_in, const int* in_sizes, int n_in,
                              void* d_out, int out_size, void* d_ws, size_t ws_size,
                              hipStream_t stream) {
    const float* z0      = (const float*)d_in[0];
    const float* t_range = (const float*)d_in[1];
    const float* W1      = (const float*)d_in[2];
    const float* b1      = (const float*)d_in[3];
    const float* wt      = (const float*)d_in[4];
    const float* W2      = (const float*)d_in[5];
    const float* b2      = (const float*)d_in[6];

    unsigned short* Wr = (unsigned short*)d_ws;
    // shorts: W1r [0,65536)  W2r [65536,131072)  W21r [131072,196608); then c1 (256 floats)
    unsigned short* W1r  = Wr;
    unsigned short* W2r  = Wr + 65536;
    unsigned short* W21r = Wr + 131072;
    float*          c1   = (float*)(Wr + 196608);

    prep_all<<<769, 256, 0, stream>>>(W1, W2, b2, t_range, Wr, W21r, c1);
    ode_main<<<512, 512, 0, stream>>>(z0, t_range, b1, wt, b2,
                                      W1r, W2r, W21r, c1, (float*)d_out);
}